// Round 8
// baseline (61.261 us; speedup 1.0000x reference)
//
#include <hip/hip_runtime.h>

// x:(8,64,56,56) f32 -> out:(8,64,49,3136) f32
// out[n,c,ki*7+kj, oh*56+ow] = x[n,c,oh,ow] - (in-bounds ? x[n,c,oh+ki-3,ow+kj-3] : 0)
//
// R7 = R4 (best: one block/plane, LDS-staged, fully sequential writes) with:
//  - halo-only LDS zeroing (770 cells vs 3906) fused with staging: disjoint
//    LDS regions -> ONE barrier instead of two.
//  - tail slice (16 f4) split 4-per-wave (lanes 0..3) inside the main loop,
//    instead of a serial 49-iteration epilogue on wave 0.

constexpr int H_ = 56, W_ = 56;
constexpr int KK_  = 49;
constexpr int OHW_ = 3136;
constexpr int PP_  = 63;               // LDS pitch (floats)
constexpr int PR_  = 62;               // padded rows -3..58
constexpr int NC_  = 512;              // 8*64 planes
constexpr int LDSN_ = PR_ * PP_;       // 3906 floats = 15.6 KB

typedef float f32x4 __attribute__((ext_vector_type(4)));

__global__ __launch_bounds__(256)
void san_kernel(const float* __restrict__ x, float* __restrict__ out) {
    __shared__ float lds[LDSN_];
    const int nc   = blockIdx.x;
    const int t    = threadIdx.x;
    const int lane = t & 63;
    const int wv   = t >> 6;

    // 1a) zero halo — full edge rows: padded rows 0..2 and 59..61, all 63 cols
    #pragma unroll
    for (int i = 0; i < 2; ++i) {
        int j = t + 256 * i;
        if (j < 378) {
            int row = j / 63, col = j - row * 63;
            int pr = row < 3 ? row : row + 56;
            lds[pr * PP_ + col] = 0.0f;
        }
    }
    // 1b) zero halo — side cols of interior rows: cols {0,1,2, 59..62}
    #pragma unroll
    for (int i = 0; i < 2; ++i) {
        int j = t + 256 * i;
        if (j < 392) {
            int rr = j / 7, cc = j - rr * 7;
            int pc = cc < 3 ? cc : cc + 56;
            lds[(3 + rr) * PP_ + pc] = 0.0f;
        }
    }

    const float* plane = x + (size_t)nc * OHW_;

    // 2) stage interior (disjoint cells from halo -> same phase, one barrier).
    //    slots: e4 = t, t+256, t+512; tail e4 = 768 + wv*4 + lane (lane<4).
    f32x4 cen0{}, cen1{}, cen2{}, cen3{};
    int wb0 = 0, wb1 = 0, wb2 = 0, wb3 = 0;
    const bool has3 = (lane < 4);
    const int e4_3 = 768 + wv * 4 + lane;

#define STAGE(E4, CEN, WB)                                          \
    {                                                               \
        int e4 = (E4);                                              \
        int oh = e4 / 14, o4 = e4 - oh * 14;                        \
        CEN = *reinterpret_cast<const f32x4*>(plane + e4 * 4);      \
        int lb = (oh + 3) * PP_ + o4 * 4 + 3;                       \
        lds[lb + 0] = CEN[0]; lds[lb + 1] = CEN[1];                 \
        lds[lb + 2] = CEN[2]; lds[lb + 3] = CEN[3];                 \
        WB = oh * PP_ + o4 * 4;                                     \
    }
    STAGE(t,        cen0, wb0)
    STAGE(t + 256,  cen1, wb1)
    STAGE(t + 512,  cen2, wb2)
    if (has3) STAGE(e4_3, cen3, wb3)
#undef STAGE
    __syncthreads();

    // 3) kk-major sweep: block writes its 614 KB region front-to-back.
    float* ob  = out + (size_t)nc * (KK_ * OHW_);
    float* op0 = ob + (size_t)(t      ) * 4;
    float* op1 = ob + (size_t)(t + 256) * 4;
    float* op2 = ob + (size_t)(t + 512) * 4;
    float* op3 = ob + (size_t)e4_3 * 4;        // stored only if has3

    #pragma unroll
    for (int ki = 0; ki < 7; ++ki) {
        #pragma unroll
        for (int kj = 0; kj < 7; ++kj) {
            const int off = ki * PP_ + kj;
            f32x4 r0, r1, r2;
            #pragma unroll
            for (int tt = 0; tt < 4; ++tt) {
                r0[tt] = cen0[tt] - lds[wb0 + off + tt];
                r1[tt] = cen1[tt] - lds[wb1 + off + tt];
                r2[tt] = cen2[tt] - lds[wb2 + off + tt];
            }
            *reinterpret_cast<f32x4*>(op0) = r0;  op0 += OHW_;
            *reinterpret_cast<f32x4*>(op1) = r1;  op1 += OHW_;
            *reinterpret_cast<f32x4*>(op2) = r2;  op2 += OHW_;
            if (has3) {
                f32x4 r3;
                #pragma unroll
                for (int tt = 0; tt < 4; ++tt)
                    r3[tt] = cen3[tt] - lds[wb3 + off + tt];
                *reinterpret_cast<f32x4*>(op3) = r3;
            }
            op3 += OHW_;
        }
    }
}

extern "C" void kernel_launch(void* const* d_in, const int* in_sizes, int n_in,
                              void* d_out, int out_size, void* d_ws, size_t ws_size,
                              hipStream_t stream) {
    const float* x = (const float*)d_in[0];
    float* out = (float*)d_out;
    san_kernel<<<NC_, 256, 0, stream>>>(x, out);
}

// Round 9
// 56.406 us; speedup vs baseline: 1.0861x; 1.0861x over previous
//
#include <hip/hip_runtime.h>

// x:(8,64,56,56) f32 -> out:(8,64,49,3136) f32
// out[n,c,ki*7+kj, oh*56+ow] = x[n,c,oh,ow] - (in-bounds ? x[n,c,oh+ki-3,ow+kj-3] : 0)
//
// R8 = R4 (best measured: one block/plane, LDS-staged, fully sequential
// 614 KB writes) with ONE structural change: the 64-float slice tail is
// stored round-robin (wave kk&3) as a single full 64-lane scalar store per
// slice, replacing R4's serial 49-iter epilogue on wave 0. Plus f32x4 LDS
// zeroing (prologue-only micro).

constexpr int H_ = 56, W_ = 56;
constexpr int KK_  = 49;
constexpr int OHW_ = 3136;
constexpr int PP_  = 63;               // LDS pitch (floats)
constexpr int PR_  = 62;               // padded rows -3..58
constexpr int NC_  = 512;              // 8*64 planes
constexpr int LDSN4 = 977;             // ceil(62*63/4) f32x4 = 3908 floats

typedef float f32x4 __attribute__((ext_vector_type(4)));

__global__ __launch_bounds__(256)
void san_kernel(const float* __restrict__ x, float* __restrict__ out) {
    __shared__ f32x4 lds4[LDSN4];
    float* lds = reinterpret_cast<float*>(lds4);
    const int nc   = blockIdx.x;
    const int t    = threadIdx.x;
    const int lane = t & 63;
    const int wv   = t >> 6;

    // 1) zero padded plane (halo stays zero -> OOB neighbors read 0)
    #pragma unroll
    for (int i = 0; i < 4; ++i) lds4[t + 256 * i] = f32x4{0.f, 0.f, 0.f, 0.f};
    if (t < LDSN4 - 1024) lds4[t + 1024] = f32x4{0.f, 0.f, 0.f, 0.f};
    __syncthreads();

    const float* plane = x + (size_t)nc * OHW_;

    // 2) stage interior; slots e4 = t, t+256, t+512 (f4), plus per-lane tail
    //    scalar: element 3072+lane (oh 54/55).
    f32x4 cen0, cen1, cen2;
    int wb0, wb1, wb2;

#define STAGE(E4, CEN, WB)                                          \
    {                                                               \
        int e4 = (E4);                                              \
        int oh = e4 / 14, o4 = e4 - oh * 14;                        \
        CEN = *reinterpret_cast<const f32x4*>(plane + e4 * 4);      \
        int lb = (oh + 3) * PP_ + o4 * 4 + 3;                       \
        lds[lb + 0] = CEN[0]; lds[lb + 1] = CEN[1];                 \
        lds[lb + 2] = CEN[2]; lds[lb + 3] = CEN[3];                 \
        WB = oh * PP_ + o4 * 4;                                     \
    }
    STAGE(t,       cen0, wb0)
    STAGE(t + 256, cen1, wb1)
    STAGE(t + 512, cen2, wb2)
#undef STAGE

    // tail element (one scalar per lane; staged by wave 0 only)
    const int tfl  = 3072 + lane;                 // flat element in slice
    const int toh  = 54 + (lane >> 3 ? 1 : 0);    // 54 for lane<8 else 55
    const int tow  = (lane < 8) ? (48 + lane) : (lane - 8);
    const float cenT = plane[tfl];
    const int  wbT = toh * PP_ + tow;
    if (wv == 0) lds[(toh + 3) * PP_ + tow + 3] = cenT;
    __syncthreads();

    // 3) kk-major sweep: block writes its 614 KB region front-to-back.
    float* ob  = out + (size_t)nc * (KK_ * OHW_);
    float* op0 = ob + (size_t)(t      ) * 4;
    float* op1 = ob + (size_t)(t + 256) * 4;
    float* op2 = ob + (size_t)(t + 512) * 4;
    float* opT = ob + tfl;

    #pragma unroll
    for (int ki = 0; ki < 7; ++ki) {
        #pragma unroll
        for (int kj = 0; kj < 7; ++kj) {
            const int off = ki * PP_ + kj;
            f32x4 r0, r1, r2;
            #pragma unroll
            for (int tt = 0; tt < 4; ++tt) {
                r0[tt] = cen0[tt] - lds[wb0 + off + tt];
                r1[tt] = cen1[tt] - lds[wb1 + off + tt];
                r2[tt] = cen2[tt] - lds[wb2 + off + tt];
            }
            *reinterpret_cast<f32x4*>(op0) = r0;  op0 += OHW_;
            *reinterpret_cast<f32x4*>(op1) = r1;  op1 += OHW_;
            *reinterpret_cast<f32x4*>(op2) = r2;  op2 += OHW_;
            // slice tail: 64 floats, one full 64-lane scalar store,
            // round-robin across waves (uniform branch per wave)
            if (wv == ((ki * 7 + kj) & 3)) {
                *opT = cenT - lds[wbT + off];
            }
            opT += OHW_;
        }
    }
}

extern "C" void kernel_launch(void* const* d_in, const int* in_sizes, int n_in,
                              void* d_out, int out_size, void* d_ws, size_t ws_size,
                              hipStream_t stream) {
    const float* x = (const float*)d_in[0];
    float* out = (float*)d_out;
    san_kernel<<<NC_, 256, 0, stream>>>(x, out);
}